// Round 3
// baseline (437.579 us; speedup 1.0000x reference)
//
#include <hip/hip_runtime.h>
#include <math.h>
#include <float.h>

#define B_  4
#define L_  1024
#define N_  16384
#define D_  256
#define K_  5
#define NCH 16
#define CHUNK (N_/NCH)      // 1024
#define RESC 16             // candidates rescored in fp32

typedef __attribute__((ext_vector_type(8))) short bf16x8;
typedef __attribute__((ext_vector_type(4))) float f32x4;

static __device__ __forceinline__ unsigned short f2bf(float f) {
    unsigned int u = __float_as_uint(f);
    unsigned int r = (u + 0x7FFFu + ((u >> 16) & 1u)) >> 16;
    return (unsigned short)r;
}

// ---------------- Kernel 1: inv norms + bf16 copies ----------------
__global__ __launch_bounds__(256) void prep_kernel(
    const float* __restrict__ enc, const float* __restrict__ mem,
    float* __restrict__ invn, unsigned short* __restrict__ memn_bf,
    unsigned short* __restrict__ enc_bf)
{
    const int row = blockIdx.x * 4 + (threadIdx.x >> 6);
    const int lane = threadIdx.x & 63;
    if (row < B_ * N_) {
        float4 v = reinterpret_cast<const float4*>(mem + (size_t)row * D_)[lane];
        float ss = v.x*v.x + v.y*v.y + v.z*v.z + v.w*v.w;
        #pragma unroll
        for (int off = 32; off; off >>= 1) ss += __shfl_xor(ss, off, 64);
        float inv = 1.0f / fmaxf(sqrtf(ss), 1e-12f);
        if (lane == 0) invn[row] = inv;
        uint2 p;
        p.x = (unsigned)f2bf(v.x*inv) | ((unsigned)f2bf(v.y*inv) << 16);
        p.y = (unsigned)f2bf(v.z*inv) | ((unsigned)f2bf(v.w*inv) << 16);
        reinterpret_cast<uint2*>(memn_bf + (size_t)row * D_)[lane] = p;
    } else {
        int r2 = row - B_ * N_;
        if (r2 >= B_ * L_) return;
        float4 v = reinterpret_cast<const float4*>(enc + (size_t)r2 * D_)[lane];
        uint2 p;
        p.x = (unsigned)f2bf(v.x) | ((unsigned)f2bf(v.y) << 16);
        p.y = (unsigned)f2bf(v.z) | ((unsigned)f2bf(v.w) << 16);
        reinterpret_cast<uint2*>(enc_bf + (size_t)r2 * D_)[lane] = p;
    }
}

// ---------------- Kernel 2: swapped-operand MFMA screen, register top-8 ----------------
// A = mem (n-dim rows), B = enc (l-dim rows) -> per-lane l-column, in-lane n-candidates.
// Packed key: (order-preserving-f32-transform & 0xFFFFFC00) | (1023 - n_local).
// grid (NCH, L/128, B), 256 thr = 4 waves (wm over n, wn over l).
__global__ __launch_bounds__(256) void screen_kernel(
    const unsigned short* __restrict__ enc_bf,
    const unsigned short* __restrict__ memn_bf,
    unsigned int* __restrict__ pcand)
{
    __shared__ __align__(16) union {
        struct { unsigned char A[128*128]; unsigned char Bt[128*128]; } st; // 32 KB
        unsigned int mg[128][67];                                           // 33.5 KB (padded)
    } sm;

    const int tid = threadIdx.x;
    const int lane = tid & 63;
    const int wv = tid >> 6;
    const int wm = wv >> 1, wn = wv & 1;   // wm: n-halves, wn: l-halves
    const int b = blockIdx.z;
    const int l0 = blockIdx.y * 128;
    const int ch = blockIdx.x;

    const int sqc = tid & 15;
    const int srow0 = tid >> 4;
    const int swr_col = (sqc * 8) ^ ((srow0 & 7) << 4);

    const int ra = wm * 64 + (lane & 15);   // A(mem) frag row base (n)
    const int rb = wn * 64 + (lane & 15);   // B(enc) frag row base (l)
    const unsigned aswz = ((unsigned)(ra & 7)) << 4;
    const unsigned bswz = ((unsigned)(rb & 7)) << 4;
    const int kgB = (lane >> 4) * 16;
    const int g4 = (lane >> 4) * 4;

    const unsigned short* encB = enc_bf + ((size_t)b * L_ + l0) * D_;
    const unsigned short* memB = memn_bf + ((size_t)b * N_ + ch * CHUNK) * D_;

    unsigned tl[4][8];   // 4 l-lists x sorted-desc top-8 packed keys
    #pragma unroll
    for (int j = 0; j < 4; ++j)
        #pragma unroll
        for (int p = 0; p < 8; ++p) tl[j][p] = 0u;

    for (int nt = 0; nt < CHUNK / 128; ++nt) {
        const int n0 = nt * 128;
        f32x4 acc[4][4];
        #pragma unroll
        for (int i = 0; i < 4; ++i)
            #pragma unroll
            for (int j = 0; j < 4; ++j) acc[i][j] = (f32x4){0.f,0.f,0.f,0.f};

        for (int kt = 0; kt < D_ / 64; ++kt) {
            const int k0 = kt * 64;
            __syncthreads();
            #pragma unroll
            for (int i = 0; i < 8; ++i) {
                int row = i * 16 + srow0;
                uint2 va = *reinterpret_cast<const uint2*>(
                    &memB[(size_t)(n0 + row) * D_ + k0 + sqc * 4]);
                *reinterpret_cast<uint2*>(sm.st.A + row * 128 + swr_col) = va;
                uint2 vb = *reinterpret_cast<const uint2*>(
                    &encB[(size_t)row * D_ + k0 + sqc * 4]);
                *reinterpret_cast<uint2*>(sm.st.Bt + row * 128 + swr_col) = vb;
            }
            __syncthreads();
            #pragma unroll
            for (int kk = 0; kk < 2; ++kk) {
                const int kb = kk * 64 + kgB;
                bf16x8 af[4], bf[4];
                #pragma unroll
                for (int m = 0; m < 4; ++m)
                    af[m] = *reinterpret_cast<const bf16x8*>(
                        sm.st.A + (ra + m * 16) * 128 + (kb ^ aswz));
                #pragma unroll
                for (int n = 0; n < 4; ++n)
                    bf[n] = *reinterpret_cast<const bf16x8*>(
                        sm.st.Bt + (rb + n * 16) * 128 + (kb ^ bswz));
                #pragma unroll
                for (int m = 0; m < 4; ++m)
                    #pragma unroll
                    for (int n = 0; n < 4; ++n)
                        acc[m][n] = __builtin_amdgcn_mfma_f32_16x16x32_bf16(
                            af[m], bf[n], acc[m][n], 0, 0, 0);
            }
        }

        // fold accumulators into per-lane packed top-8 lists
        #pragma unroll
        for (int j = 0; j < 4; ++j) {
            #pragma unroll
            for (int i = 0; i < 4; ++i) {
                f32x4 v = acc[i][j];
                const int invb = 1023 - (n0 + wm * 64 + i * 16 + g4);
                #pragma unroll
                for (int r = 0; r < 4; ++r) {
                    unsigned u = __float_as_uint(v[r]);
                    unsigned t = u ^ ((unsigned)(((int)u) >> 31) | 0x80000000u);
                    unsigned key = (t & 0xFFFFFC00u) | (unsigned)(invb - r);
                    if (key > tl[j][7]) {
                        int pos = 0;
                        #pragma unroll
                        for (int p = 0; p < 8; ++p) pos += (tl[j][p] >= key) ? 1 : 0;
                        #pragma unroll
                        for (int p = 7; p >= 1; --p)
                            if (p > pos) tl[j][p] = tl[j][p-1];
                        #pragma unroll
                        for (int p = 0; p < 8; ++p)
                            if (p == pos) tl[j][p] = key;
                    }
                }
            }
        }
    }

    __syncthreads();   // staging LDS dead; reuse as merge buffer
    {
        const int c = lane & 15;
        const int src = wm * 4 + (lane >> 4);
        #pragma unroll
        for (int j = 0; j < 4; ++j) {
            const int l = wn * 64 + j * 16 + c;
            #pragma unroll
            for (int p = 0; p < 8; ++p)
                sm.mg[l][src * 8 + p] = tl[j][p];
        }
    }
    __syncthreads();

    if (tid < 128) {
        unsigned best[8];
        #pragma unroll
        for (int p = 0; p < 8; ++p) best[p] = 0u;
        #pragma unroll 4
        for (int c = 0; c < 64; ++c) {
            unsigned key = sm.mg[tid][c];
            if (key > best[7]) {
                int pos = 0;
                #pragma unroll
                for (int p = 0; p < 8; ++p) pos += (best[p] >= key) ? 1 : 0;
                #pragma unroll
                for (int p = 7; p >= 1; --p)
                    if (p > pos) best[p] = best[p-1];
                #pragma unroll
                for (int p = 0; p < 8; ++p)
                    if (p == pos) best[p] = key;
            }
        }
        size_t gb = (((size_t)b * L_ + l0 + tid) * NCH + ch) * 8;
        #pragma unroll
        for (int p = 0; p < 8; ++p) pcand[gb + p] = best[p];
    }
}

// ---------------- Kernel 3: u32 extract top-16, fp32 rescore, top-5, gather+mean ----------------
__global__ __launch_bounds__(256) void rescore_kernel(
    const float* __restrict__ enc, const float* __restrict__ mem,
    const float* __restrict__ invn,
    const unsigned int* __restrict__ pcand,
    float* __restrict__ tbuf)
{
    __shared__ int cand_lds[4][RESC];
    const int wv = threadIdx.x >> 6;
    const int lane = threadIdx.x & 63;
    const int row = blockIdx.x * 4 + wv;       // 0..4095
    const int b = row >> 10;
    const int l = row & 1023;

    const size_t cb = (size_t)row * (NCH * 8);
    unsigned k0 = pcand[cb + lane], k1 = pcand[cb + 64 + lane];

    #pragma unroll
    for (int rr = 0; rr < RESC; ++rr) {
        unsigned mv; int mi;
        bool t0 = (k0 >= k1);
        mv = t0 ? k0 : k1; mi = t0 ? lane : 64 + lane;
        #pragma unroll
        for (int off = 32; off; off >>= 1) {
            unsigned ov = __shfl_xor(mv, off, 64);
            int oi = __shfl_xor(mi, off, 64);
            if (ov > mv || (ov == mv && oi < mi)) { mv = ov; mi = oi; }
        }
        if (lane == 0) {
            int chunk = mi >> 3;
            cand_lds[wv][rr] = chunk * CHUNK + (CHUNK - 1) - (int)(mv & 0x3FFu);
        }
        if (mi == lane) k0 = 0u;
        if (mi == 64 + lane) k1 = 0u;
    }
    __syncthreads();

    // fp32 rescore: lane handles candidate lane>>2, quarter lane&3
    const int ci = cand_lds[wv][lane >> 2];
    const int q = lane & 3;
    const float4* er = reinterpret_cast<const float4*>(enc + ((size_t)b * L_ + l) * D_) + q * 16;
    const float4* mr = reinterpret_cast<const float4*>(mem + ((size_t)b * N_ + ci) * D_) + q * 16;
    float s = 0.0f;
    #pragma unroll
    for (int k = 0; k < 16; ++k) {
        float4 e = er[k], m = mr[k];
        s = fmaf(e.x, m.x, s); s = fmaf(e.y, m.y, s);
        s = fmaf(e.z, m.z, s); s = fmaf(e.w, m.w, s);
    }
    s += __shfl_xor(s, 1, 64);
    s += __shfl_xor(s, 2, 64);
    s *= invn[b * N_ + ci];

    float sw = s;
    int m0, m1, m2, m3, m4;
    #define PICK(MK) { \
        float mv = sw; int mi = ci; \
        if (sw == -FLT_MAX) mi = 0x7fffffff; \
        _Pragma("unroll") \
        for (int off = 32; off; off >>= 1) { \
            float ov = __shfl_xor(mv, off, 64); \
            int oi = __shfl_xor(mi, off, 64); \
            if (ov > mv || (ov == mv && oi < mi)) { mv = ov; mi = oi; } \
        } \
        MK = mi; \
        if (ci == mi) sw = -FLT_MAX; \
    }
    PICK(m0); PICK(m1); PICK(m2); PICK(m3); PICK(m4);
    #undef PICK

    const float4* eb = reinterpret_cast<const float4*>(enc + ((size_t)b * L_ + l) * D_);
    const float4* mb = reinterpret_cast<const float4*>(mem + (size_t)b * N_ * D_);
    float4 e = eb[lane];
    float4 a0 = mb[(size_t)m0 * 64 + lane];
    float4 a1 = mb[(size_t)m1 * 64 + lane];
    float4 a2 = mb[(size_t)m2 * 64 + lane];
    float4 a3 = mb[(size_t)m3 * 64 + lane];
    float4 a4 = mb[(size_t)m4 * 64 + lane];
    float4 o;
    o.x = e.x + 0.2f * (a0.x + a1.x + a2.x + a3.x + a4.x);
    o.y = e.y + 0.2f * (a0.y + a1.y + a2.y + a3.y + a4.y);
    o.z = e.z + 0.2f * (a0.z + a1.z + a2.z + a3.z + a4.z);
    o.w = e.w + 0.2f * (a0.w + a1.w + a2.w + a3.w + a4.w);
    reinterpret_cast<float4*>(tbuf + (size_t)row * D_)[lane] = o;
}

// ---------------- Kernel 4: linear out = t @ W^T + b ----------------
__global__ __launch_bounds__(256) void linear_kernel(
    const float* __restrict__ tbuf, const float* __restrict__ W,
    const float* __restrict__ bias, float* __restrict__ out)
{
    __shared__ float t_s[16][D_];
    const int blk = blockIdx.x;
    const int b = blk >> 6;
    const int r0 = (blk & 63) << 4;
    const int tid = threadIdx.x;

    #pragma unroll
    for (int k = 0; k < 4; ++k) {
        int idx = k * 256 + tid;
        int row = idx >> 6, c4 = idx & 63;
        float4 v = reinterpret_cast<const float4*>(
            tbuf + ((size_t)b * L_ + r0 + row) * D_)[c4];
        *reinterpret_cast<float4*>(&t_s[row][c4 * 4]) = v;
    }
    __syncthreads();

    const int dout = tid;
    float accr[16];
    #pragma unroll
    for (int r = 0; r < 16; ++r) accr[r] = 0.0f;
    const float4* Wr = reinterpret_cast<const float4*>(W + (size_t)dout * D_);
    for (int d4 = 0; d4 < D_ / 4; ++d4) {
        float4 w = Wr[d4];
        #pragma unroll
        for (int r = 0; r < 16; ++r) {
            float4 t = *reinterpret_cast<const float4*>(&t_s[r][d4 * 4]);
            accr[r] = fmaf(w.x, t.x, accr[r]);
            accr[r] = fmaf(w.y, t.y, accr[r]);
            accr[r] = fmaf(w.z, t.z, accr[r]);
            accr[r] = fmaf(w.w, t.w, accr[r]);
        }
    }
    float bb = bias[dout];
    #pragma unroll
    for (int r = 0; r < 16; ++r)
        out[((size_t)b * L_ + r0 + r) * D_ + dout] = accr[r] + bb;
}

extern "C" void kernel_launch(void* const* d_in, const int* in_sizes, int n_in,
                              void* d_out, int out_size, void* d_ws, size_t ws_size,
                              hipStream_t stream)
{
    (void)in_sizes; (void)n_in; (void)out_size;
    const float* enc  = (const float*)d_in[0];
    const float* mem  = (const float*)d_in[1];
    const float* W    = (const float*)d_in[2];
    const float* bias = (const float*)d_in[3];
    float* out = (float*)d_out;

    const size_t sz_memn = (size_t)B_ * N_ * D_ * 2;        // 32 MiB
    const size_t sz_enc  = (size_t)B_ * L_ * D_ * 2;        // 2 MiB
    const size_t sz_invn = (size_t)B_ * N_ * 4;             // 256 KiB
    const size_t sz_pc   = (size_t)B_ * L_ * NCH * 8 * 4;   // 2 MiB
    const size_t sz_tbuf = (size_t)B_ * L_ * D_ * 4;        // 4 MiB
    const size_t need = sz_memn + sz_enc + sz_invn + sz_pc + sz_tbuf;
    if (ws_size < need) return;

    char* p = (char*)d_ws;
    unsigned short* memn_bf = (unsigned short*)p;  p += sz_memn;
    unsigned short* enc_bf  = (unsigned short*)p;  p += sz_enc;
    float* invn = (float*)p;  p += sz_invn;
    unsigned int* pcand = (unsigned int*)p;  p += sz_pc;
    float* tbuf = (float*)p;

    {
        int rows = B_ * N_ + B_ * L_;
        prep_kernel<<<(rows + 3) / 4, 256, 0, stream>>>(enc, mem, invn, memn_bf, enc_bf);
    }
    {
        dim3 grid(NCH, L_ / 128, B_);
        screen_kernel<<<grid, 256, 0, stream>>>(enc_bf, memn_bf, pcand);
    }
    {
        rescore_kernel<<<(B_ * L_) / 4, 256, 0, stream>>>(enc, mem, invn, pcand, tbuf);
    }
    {
        linear_kernel<<<B_ * L_ / 16, 256, 0, stream>>>(tbuf, W, bias, out);
    }
}

// Round 4
// 206.664 us; speedup vs baseline: 2.1173x; 2.1173x over previous
//
#include <hip/hip_runtime.h>
#include <math.h>
#include <float.h>

#define B_  4
#define L_  1024
#define N_  16384
#define D_  256
#define K_  5
#define NCH 16
#define CHUNK (N_/NCH)      // 1024
#define RESC 16             // candidates rescored in fp32

typedef __attribute__((ext_vector_type(8))) short bf16x8;
typedef __attribute__((ext_vector_type(4))) float f32x4;

static __device__ __forceinline__ unsigned short f2bf(float f) {
    unsigned int u = __float_as_uint(f);
    unsigned int r = (u + 0x7FFFu + ((u >> 16) & 1u)) >> 16;
    return (unsigned short)r;
}

// ---------------- Kernel 1: inv norms + bf16 copies ----------------
__global__ __launch_bounds__(256) void prep_kernel(
    const float* __restrict__ enc, const float* __restrict__ mem,
    float* __restrict__ invn, unsigned short* __restrict__ memn_bf,
    unsigned short* __restrict__ enc_bf)
{
    const int row = blockIdx.x * 4 + (threadIdx.x >> 6);
    const int lane = threadIdx.x & 63;
    if (row < B_ * N_) {
        float4 v = reinterpret_cast<const float4*>(mem + (size_t)row * D_)[lane];
        float ss = v.x*v.x + v.y*v.y + v.z*v.z + v.w*v.w;
        #pragma unroll
        for (int off = 32; off; off >>= 1) ss += __shfl_xor(ss, off, 64);
        float inv = 1.0f / fmaxf(sqrtf(ss), 1e-12f);
        if (lane == 0) invn[row] = inv;
        uint2 p;
        p.x = (unsigned)f2bf(v.x*inv) | ((unsigned)f2bf(v.y*inv) << 16);
        p.y = (unsigned)f2bf(v.z*inv) | ((unsigned)f2bf(v.w*inv) << 16);
        reinterpret_cast<uint2*>(memn_bf + (size_t)row * D_)[lane] = p;
    } else {
        int r2 = row - B_ * N_;
        if (r2 >= B_ * L_) return;
        float4 v = reinterpret_cast<const float4*>(enc + (size_t)r2 * D_)[lane];
        uint2 p;
        p.x = (unsigned)f2bf(v.x) | ((unsigned)f2bf(v.y) << 16);
        p.y = (unsigned)f2bf(v.z) | ((unsigned)f2bf(v.w) << 16);
        reinterpret_cast<uint2*>(enc_bf + (size_t)r2 * D_)[lane] = p;
    }
}

// ---------------- Kernel 2: swapped-operand MFMA screen, branchless top-5 ----------------
// A = mem (n rows), B = enc (l cols). Scores land lane-local in fp32 accs.
// Key = (bits(score + 64.0f) & 0xFFFFFC00) | (1023 - n_local)  -- monotone since
// score+64 > 0; larger key = larger score, tie -> smaller n. Per-lane branchless
// top-5 cascade (exact chunk-top-5 guarantee), block merge -> per-chunk top-8.
__global__ __launch_bounds__(256, 2) void screen_kernel(
    const unsigned short* __restrict__ enc_bf,
    const unsigned short* __restrict__ memn_bf,
    unsigned int* __restrict__ pcand)
{
    __shared__ __align__(16) union {
        struct { unsigned char A[128*128]; unsigned char Bt[128*128]; } st; // 32 KB
        unsigned int mg[128][41];                                           // 21 KB (padded)
    } sm;

    const int tid = threadIdx.x;
    const int lane = tid & 63;
    const int wv = tid >> 6;
    const int wm = wv >> 1, wn = wv & 1;   // wm: n-halves, wn: l-halves
    const int b = blockIdx.z;
    const int l0 = blockIdx.y * 128;
    const int ch = blockIdx.x;

    // staging: uint4 units; row = sr0 + i*32, 16B quad sq
    const int sq = tid & 7;
    const int sr0 = tid >> 3;           // 0..31

    const int ra = wm * 64 + (lane & 15);   // A(mem) frag row base (n)
    const int rb = wn * 64 + (lane & 15);   // B(enc) frag row base (l)
    const unsigned aswz = ((unsigned)(ra & 7)) << 4;
    const unsigned bswz = ((unsigned)(rb & 7)) << 4;
    const int kgB = (lane >> 4) * 16;
    const int g4 = (lane >> 4) * 4;

    const unsigned short* encB = enc_bf + ((size_t)b * L_ + l0) * D_;
    const unsigned short* memB = memn_bf + ((size_t)b * N_ + ch * CHUNK) * D_;

    unsigned tl[4][5];   // 4 l-lists x sorted-desc top-5 packed keys
    #pragma unroll
    for (int j = 0; j < 4; ++j)
        #pragma unroll
        for (int p = 0; p < 5; ++p) tl[j][p] = 0u;

    for (int nt = 0; nt < CHUNK / 128; ++nt) {
        const int n0 = nt * 128;
        f32x4 acc[4][4];
        #pragma unroll
        for (int i = 0; i < 4; ++i)
            #pragma unroll
            for (int j = 0; j < 4; ++j) acc[i][j] = (f32x4){0.f,0.f,0.f,0.f};

        for (int kt = 0; kt < D_ / 64; ++kt) {
            const int k0 = kt * 64;
            __syncthreads();
            #pragma unroll
            for (int i = 0; i < 4; ++i) {
                const int row = sr0 + i * 32;
                const int colw = (sq * 16) ^ ((row & 7) << 4);
                uint4 va = *reinterpret_cast<const uint4*>(
                    &memB[(size_t)(n0 + row) * D_ + k0 + sq * 8]);
                *reinterpret_cast<uint4*>(sm.st.A + row * 128 + colw) = va;
                uint4 vb = *reinterpret_cast<const uint4*>(
                    &encB[(size_t)row * D_ + k0 + sq * 8]);
                *reinterpret_cast<uint4*>(sm.st.Bt + row * 128 + colw) = vb;
            }
            __syncthreads();
            #pragma unroll
            for (int kk = 0; kk < 2; ++kk) {
                const int kb = kk * 64 + kgB;
                bf16x8 af[4], bfv[4];
                #pragma unroll
                for (int m = 0; m < 4; ++m)
                    af[m] = *reinterpret_cast<const bf16x8*>(
                        sm.st.A + (ra + m * 16) * 128 + (kb ^ aswz));
                #pragma unroll
                for (int n = 0; n < 4; ++n)
                    bfv[n] = *reinterpret_cast<const bf16x8*>(
                        sm.st.Bt + (rb + n * 16) * 128 + (kb ^ bswz));
                #pragma unroll
                for (int m = 0; m < 4; ++m)
                    #pragma unroll
                    for (int n = 0; n < 4; ++n)
                        acc[m][n] = __builtin_amdgcn_mfma_f32_16x16x32_bf16(
                            af[m], bfv[n], acc[m][n], 0, 0, 0);
            }
        }

        // branchless fold: 64 scores/lane -> 4 per-lane top-5 lists
        const unsigned inv_base = 1023u - (unsigned)(n0 + wm * 64 + g4);
        #pragma unroll
        for (int i = 0; i < 4; ++i) {
            #pragma unroll
            for (int r = 0; r < 4; ++r) {
                const unsigned idxv = inv_base - (unsigned)(i * 16 + r);
                #pragma unroll
                for (int j = 0; j < 4; ++j) {       // j innermost: 4-way ILP
                    float fb = acc[i][j][r] + 64.0f;
                    unsigned c = (__float_as_uint(fb) & 0xFFFFFC00u) | idxv;
                    #pragma unroll
                    for (int p = 0; p < 5; ++p) {
                        unsigned mx = tl[j][p] > c ? tl[j][p] : c;
                        unsigned mn = tl[j][p] > c ? c : tl[j][p];
                        tl[j][p] = mx; c = mn;
                    }
                }
            }
        }
    }

    __syncthreads();   // staging LDS dead; reuse as merge buffer
    {
        const int c = lane & 15;
        const int src = wm * 4 + (lane >> 4);      // 0..7
        #pragma unroll
        for (int j = 0; j < 4; ++j) {
            const int l = wn * 64 + j * 16 + c;
            #pragma unroll
            for (int p = 0; p < 5; ++p)
                sm.mg[l][src * 5 + p] = tl[j][p];
        }
    }
    __syncthreads();

    if (tid < 128) {
        unsigned best[8];
        #pragma unroll
        for (int p = 0; p < 8; ++p) best[p] = 0u;
        #pragma unroll
        for (int c = 0; c < 40; ++c) {
            unsigned key = sm.mg[tid][c];
            #pragma unroll
            for (int p = 0; p < 8; ++p) {
                unsigned mx = best[p] > key ? best[p] : key;
                unsigned mn = best[p] > key ? key : best[p];
                best[p] = mx; key = mn;
            }
        }
        size_t gb = (((size_t)b * L_ + l0 + tid) * NCH + ch) * 8;
        #pragma unroll
        for (int p = 0; p < 8; ++p) pcand[gb + p] = best[p];
    }
}

// ---------------- Kernel 3: u32 extract top-16, fp32 rescore, top-5, gather+mean ----------------
__global__ __launch_bounds__(256) void rescore_kernel(
    const float* __restrict__ enc, const float* __restrict__ mem,
    const float* __restrict__ invn,
    const unsigned int* __restrict__ pcand,
    float* __restrict__ tbuf)
{
    __shared__ int cand_lds[4][RESC];
    const int wv = threadIdx.x >> 6;
    const int lane = threadIdx.x & 63;
    const int row = blockIdx.x * 4 + wv;       // 0..4095
    const int b = row >> 10;
    const int l = row & 1023;

    const size_t cb = (size_t)row * (NCH * 8);
    unsigned k0 = pcand[cb + lane], k1 = pcand[cb + 64 + lane];

    #pragma unroll
    for (int rr = 0; rr < RESC; ++rr) {
        unsigned mv; int mi;
        bool t0 = (k0 >= k1);
        mv = t0 ? k0 : k1; mi = t0 ? lane : 64 + lane;
        #pragma unroll
        for (int off = 32; off; off >>= 1) {
            unsigned ov = __shfl_xor(mv, off, 64);
            int oi = __shfl_xor(mi, off, 64);
            if (ov > mv || (ov == mv && oi < mi)) { mv = ov; mi = oi; }
        }
        if (lane == 0) {
            int chunk = mi >> 3;
            cand_lds[wv][rr] = chunk * CHUNK + (CHUNK - 1) - (int)(mv & 0x3FFu);
        }
        if (mi == lane) k0 = 0u;
        if (mi == 64 + lane) k1 = 0u;
    }
    __syncthreads();

    // fp32 rescore: lane handles candidate lane>>2, quarter lane&3
    const int ci = cand_lds[wv][lane >> 2];
    const int q = lane & 3;
    const float4* er = reinterpret_cast<const float4*>(enc + ((size_t)b * L_ + l) * D_) + q * 16;
    const float4* mr = reinterpret_cast<const float4*>(mem + ((size_t)b * N_ + ci) * D_) + q * 16;
    float s = 0.0f;
    #pragma unroll
    for (int k = 0; k < 16; ++k) {
        float4 e = er[k], m = mr[k];
        s = fmaf(e.x, m.x, s); s = fmaf(e.y, m.y, s);
        s = fmaf(e.z, m.z, s); s = fmaf(e.w, m.w, s);
    }
    s += __shfl_xor(s, 1, 64);
    s += __shfl_xor(s, 2, 64);
    s *= invn[b * N_ + ci];

    float sw = s;
    int m0, m1, m2, m3, m4;
    #define PICK(MK) { \
        float mv = sw; int mi = ci; \
        if (sw == -FLT_MAX) mi = 0x7fffffff; \
        _Pragma("unroll") \
        for (int off = 32; off; off >>= 1) { \
            float ov = __shfl_xor(mv, off, 64); \
            int oi = __shfl_xor(mi, off, 64); \
            if (ov > mv || (ov == mv && oi < mi)) { mv = ov; mi = oi; } \
        } \
        MK = mi; \
        if (ci == mi) sw = -FLT_MAX; \
    }
    PICK(m0); PICK(m1); PICK(m2); PICK(m3); PICK(m4);
    #undef PICK

    const float4* eb = reinterpret_cast<const float4*>(enc + ((size_t)b * L_ + l) * D_);
    const float4* mb = reinterpret_cast<const float4*>(mem + (size_t)b * N_ * D_);
    float4 e = eb[lane];
    float4 a0 = mb[(size_t)m0 * 64 + lane];
    float4 a1 = mb[(size_t)m1 * 64 + lane];
    float4 a2 = mb[(size_t)m2 * 64 + lane];
    float4 a3 = mb[(size_t)m3 * 64 + lane];
    float4 a4 = mb[(size_t)m4 * 64 + lane];
    float4 o;
    o.x = e.x + 0.2f * (a0.x + a1.x + a2.x + a3.x + a4.x);
    o.y = e.y + 0.2f * (a0.y + a1.y + a2.y + a3.y + a4.y);
    o.z = e.z + 0.2f * (a0.z + a1.z + a2.z + a3.z + a4.z);
    o.w = e.w + 0.2f * (a0.w + a1.w + a2.w + a3.w + a4.w);
    reinterpret_cast<float4*>(tbuf + (size_t)row * D_)[lane] = o;
}

// ---------------- Kernel 4: linear out = t @ W^T + b (512 thr) ----------------
__global__ __launch_bounds__(512) void linear_kernel(
    const float* __restrict__ tbuf, const float* __restrict__ W,
    const float* __restrict__ bias, float* __restrict__ out)
{
    __shared__ float t_s[16][D_];
    const int blk = blockIdx.x;
    const int b = blk >> 6;
    const int r0 = (blk & 63) << 4;
    const int tid = threadIdx.x;

    #pragma unroll
    for (int k = 0; k < 2; ++k) {
        int idx = k * 512 + tid;
        int row = idx >> 6, c4 = idx & 63;
        float4 v = reinterpret_cast<const float4*>(
            tbuf + ((size_t)b * L_ + r0 + row) * D_)[c4];
        *reinterpret_cast<float4*>(&t_s[row][c4 * 4]) = v;
    }
    __syncthreads();

    const int dout = tid & 255;
    const int half = tid >> 8;         // rows half*8 .. +8
    float accr[8];
    #pragma unroll
    for (int r = 0; r < 8; ++r) accr[r] = 0.0f;
    const float4* Wr = reinterpret_cast<const float4*>(W + (size_t)dout * D_);
    for (int d4 = 0; d4 < D_ / 4; ++d4) {
        float4 w = Wr[d4];
        #pragma unroll
        for (int r = 0; r < 8; ++r) {
            float4 t = *reinterpret_cast<const float4*>(&t_s[half * 8 + r][d4 * 4]);
            accr[r] = fmaf(w.x, t.x, accr[r]);
            accr[r] = fmaf(w.y, t.y, accr[r]);
            accr[r] = fmaf(w.z, t.z, accr[r]);
            accr[r] = fmaf(w.w, t.w, accr[r]);
        }
    }
    float bb = bias[dout];
    #pragma unroll
    for (int r = 0; r < 8; ++r)
        out[((size_t)b * L_ + r0 + half * 8 + r) * D_ + dout] = accr[r] + bb;
}

extern "C" void kernel_launch(void* const* d_in, const int* in_sizes, int n_in,
                              void* d_out, int out_size, void* d_ws, size_t ws_size,
                              hipStream_t stream)
{
    (void)in_sizes; (void)n_in; (void)out_size;
    const float* enc  = (const float*)d_in[0];
    const float* mem  = (const float*)d_in[1];
    const float* W    = (const float*)d_in[2];
    const float* bias = (const float*)d_in[3];
    float* out = (float*)d_out;

    const size_t sz_memn = (size_t)B_ * N_ * D_ * 2;        // 32 MiB
    const size_t sz_enc  = (size_t)B_ * L_ * D_ * 2;        // 2 MiB
    const size_t sz_invn = (size_t)B_ * N_ * 4;             // 256 KiB
    const size_t sz_pc   = (size_t)B_ * L_ * NCH * 8 * 4;   // 2 MiB
    const size_t sz_tbuf = (size_t)B_ * L_ * D_ * 4;        // 4 MiB
    const size_t need = sz_memn + sz_enc + sz_invn + sz_pc + sz_tbuf;
    if (ws_size < need) return;

    char* p = (char*)d_ws;
    unsigned short* memn_bf = (unsigned short*)p;  p += sz_memn;
    unsigned short* enc_bf  = (unsigned short*)p;  p += sz_enc;
    float* invn = (float*)p;  p += sz_invn;
    unsigned int* pcand = (unsigned int*)p;  p += sz_pc;
    float* tbuf = (float*)p;

    {
        int rows = B_ * N_ + B_ * L_;
        prep_kernel<<<(rows + 3) / 4, 256, 0, stream>>>(enc, mem, invn, memn_bf, enc_bf);
    }
    {
        dim3 grid(NCH, L_ / 128, B_);
        screen_kernel<<<grid, 256, 0, stream>>>(enc_bf, memn_bf, pcand);
    }
    {
        rescore_kernel<<<(B_ * L_) / 4, 256, 0, stream>>>(enc, mem, invn, pcand, tbuf);
    }
    {
        linear_kernel<<<B_ * L_ / 16, 512, 0, stream>>>(tbuf, W, bias, out);
    }
}

// Round 6
// 196.156 us; speedup vs baseline: 2.2308x; 1.0536x over previous
//
#include <hip/hip_runtime.h>
#include <math.h>
#include <float.h>

#define B_  4
#define L_  1024
#define N_  16384
#define D_  256
#define K_  5
#define NCH 16
#define CHUNK (N_/NCH)      // 1024
#define RESC 16             // candidates rescored in fp32

typedef __attribute__((ext_vector_type(8))) short bf16x8;
typedef __attribute__((ext_vector_type(4))) float f32x4;

static __device__ __forceinline__ unsigned short f2bf(float f) {
    unsigned int u = __float_as_uint(f);
    unsigned int r = (u + 0x7FFFu + ((u >> 16) & 1u)) >> 16;
    return (unsigned short)r;
}

static __device__ __forceinline__ void gld16(const void* g, void* l) {
    __builtin_amdgcn_global_load_lds(
        (const __attribute__((address_space(1))) unsigned int*)g,
        (__attribute__((address_space(3))) unsigned int*)l, 16, 0, 0);
}

// ---------------- Kernel 1: inv norms + bf16 copies ----------------
__global__ __launch_bounds__(256) void prep_kernel(
    const float* __restrict__ enc, const float* __restrict__ mem,
    float* __restrict__ invn, unsigned short* __restrict__ memn_bf,
    unsigned short* __restrict__ enc_bf)
{
    const int row = blockIdx.x * 4 + (threadIdx.x >> 6);
    const int lane = threadIdx.x & 63;
    if (row < B_ * N_) {
        float4 v = reinterpret_cast<const float4*>(mem + (size_t)row * D_)[lane];
        float ss = v.x*v.x + v.y*v.y + v.z*v.z + v.w*v.w;
        #pragma unroll
        for (int off = 32; off; off >>= 1) ss += __shfl_xor(ss, off, 64);
        float inv = 1.0f / fmaxf(sqrtf(ss), 1e-12f);
        if (lane == 0) invn[row] = inv;
        uint2 p;
        p.x = (unsigned)f2bf(v.x*inv) | ((unsigned)f2bf(v.y*inv) << 16);
        p.y = (unsigned)f2bf(v.z*inv) | ((unsigned)f2bf(v.w*inv) << 16);
        reinterpret_cast<uint2*>(memn_bf + (size_t)row * D_)[lane] = p;
    } else {
        int r2 = row - B_ * N_;
        if (r2 >= B_ * L_) return;
        float4 v = reinterpret_cast<const float4*>(enc + (size_t)r2 * D_)[lane];
        uint2 p;
        p.x = (unsigned)f2bf(v.x) | ((unsigned)f2bf(v.y) << 16);
        p.y = (unsigned)f2bf(v.z) | ((unsigned)f2bf(v.w) << 16);
        reinterpret_cast<uint2*>(enc_bf + (size_t)r2 * D_)[lane] = p;
    }
}

// ---------------- Kernel 2: pipelined MFMA screen ----------------
// A = mem (n rows) staged per k-step via global_load_lds (pre-swizzled source),
// B = enc staged ONCE (full K) in LDS. Fold of tile nt-1's acc interleaved
// into tile nt's MFMA region (separate pipes overlap).
// Key = (bits(max(s,0)) & 0xFFFFFC00) | (1023 - n_local); per-lane branchless top-5.
#define SCREEN_TILE(N0, ACC, PACC, PN0, DOFOLD)                                        \
  {                                                                                    \
    _Pragma("unroll")                                                                  \
    for (int i_ = 0; i_ < 4; ++i_)                                                     \
      _Pragma("unroll")                                                                \
      for (int j_ = 0; j_ < 4; ++j_) ACC[i_][j_] = (f32x4){0.f, 0.f, 0.f, 0.f};        \
    const char* memT_ = memBb + (size_t)(N0) * (D_ * 2);                               \
    _Pragma("unroll")                                                                  \
    for (int kt = 0; kt < 4; ++kt) {                                                   \
      __syncthreads();                                                                 \
      _Pragma("unroll")                                                                \
      for (int c_ = 0; c_ < 4; ++c_) {                                                 \
        int s_ = c_ * 4 + wv;                                                          \
        gld16(memT_ + (size_t)(s_ * 8 + (lane >> 3)) * (D_ * 2) + kt * 128 + scolA,    \
              sA + s_ * 1024);                                                         \
      }                                                                                \
      __syncthreads();                                                                 \
      _Pragma("unroll")                                                                \
      for (int kk = 0; kk < 2; ++kk) {                                                 \
        const int kbA_ = kk * 64 + kgB;                                                \
        const int cB_ = kt * 128 + kk * 64 + kgB;                                      \
        bf16x8 af_[4], bfv_[4];                                                        \
        _Pragma("unroll")                                                              \
        for (int m_ = 0; m_ < 4; ++m_)                                                 \
          af_[m_] = *reinterpret_cast<const bf16x8*>(                                  \
              sA + (ra + m_ * 16) * 128 + (kbA_ ^ aswz));                              \
        _Pragma("unroll")                                                              \
        for (int n_ = 0; n_ < 4; ++n_)                                                 \
          bfv_[n_] = *reinterpret_cast<const bf16x8*>(                                 \
              sEnc + (rb + n_ * 16) * 512 + (cB_ ^ bswz));                             \
        _Pragma("unroll")                                                              \
        for (int m_ = 0; m_ < 4; ++m_)                                                 \
          _Pragma("unroll")                                                            \
          for (int n_ = 0; n_ < 4; ++n_)                                               \
            ACC[m_][n_] = __builtin_amdgcn_mfma_f32_16x16x32_bf16(                     \
                af_[m_], bfv_[n_], ACC[m_][n_], 0, 0, 0);                              \
      }                                                                                \
      if (DOFOLD) {                                                                    \
        const unsigned ibase_ = 1023u - (unsigned)((PN0) + wm * 64 + kt * 16 + g4);    \
        _Pragma("unroll")                                                              \
        for (int r_ = 0; r_ < 4; ++r_) {                                               \
          const unsigned idxv_ = ibase_ - (unsigned)r_;                                \
          _Pragma("unroll")                                                            \
          for (int j_ = 0; j_ < 4; ++j_) {                                             \
            unsigned c2_ = (__float_as_uint(fmaxf(PACC[kt][j_][r_], 0.0f))             \
                            & 0xFFFFFC00u) | idxv_;                                    \
            _Pragma("unroll")                                                          \
            for (int p_ = 0; p_ < 5; ++p_) {                                           \
              unsigned mx_ = tl[j_][p_] > c2_ ? tl[j_][p_] : c2_;                      \
              unsigned mn_ = tl[j_][p_] > c2_ ? c2_ : tl[j_][p_];                      \
              tl[j_][p_] = mx_; c2_ = mn_;                                             \
            }                                                                          \
          }                                                                            \
        }                                                                              \
      }                                                                                \
    }                                                                                  \
  }

__global__ __launch_bounds__(256, 2) void screen_kernel(
    const unsigned short* __restrict__ enc_bf,
    const unsigned short* __restrict__ memn_bf,
    unsigned int* __restrict__ pcand)
{
    __shared__ __align__(16) unsigned char smem[16*1024 + 64*1024]; // sA 16K, sEnc 64K
    unsigned char* sA = smem;
    unsigned char* sEnc = smem + 16*1024;

    const int tid = threadIdx.x;
    const int lane = tid & 63;
    const int wv = tid >> 6;
    const int wm = wv >> 1, wn = wv & 1;   // wm: n-halves, wn: l-halves
    const int b = blockIdx.z;
    const int l0 = blockIdx.y * 128;
    const int ch = blockIdx.x;

    const int ra = wm * 64 + (lane & 15);   // A(mem) frag row base (n-local)
    const int rb = wn * 64 + (lane & 15);   // B(enc) frag row base (l-local)
    const unsigned aswz = ((unsigned)(ra & 7)) << 4;
    const unsigned bswz = ((unsigned)(rb & 7)) << 4;
    const int kgB = (lane >> 4) * 16;
    const int g4 = (lane >> 4) * 4;
    const int scolA = ((lane & 7) * 16) ^ ((lane >> 3) << 4);  // pre-swizzled src col

    const char* encBb = (const char*)(enc_bf + ((size_t)b * L_ + l0) * D_);
    const char* memBb = (const char*)(memn_bf + ((size_t)b * N_ + ch * CHUNK) * D_);

    // stage full enc tile (128 rows x 256 cols bf16 = 64 KB) once, swizzled source
    #pragma unroll
    for (int c = 0; c < 16; ++c) {
        int s = c * 4 + wv;
        int row = s * 2 + (lane >> 5);
        int col = ((lane & 31) * 16) ^ ((row & 7) << 4);
        gld16(encBb + (size_t)row * 512 + col, sEnc + s * 1024);
    }

    unsigned tl[4][5];
    #pragma unroll
    for (int j = 0; j < 4; ++j)
        #pragma unroll
        for (int p = 0; p < 5; ++p) tl[j][p] = 0u;

    f32x4 accA[4][4], accB[4][4];

    SCREEN_TILE(0, accA, accB, 0, false)
    {
        int n0v = 128, pn0v = 0;
        #pragma unroll 1
        for (int it = 0; it < 3; ++it) {
            SCREEN_TILE(n0v, accB, accA, pn0v, true)
            SCREEN_TILE(n0v + 128, accA, accB, pn0v + 128, true)
            n0v += 256; pn0v += 256;
        }
    }
    SCREEN_TILE(896, accB, accA, 768, true)

    // epilogue: fold tile 7 (accB)
    {
        #pragma unroll
        for (int i = 0; i < 4; ++i) {
            const unsigned ibase = 1023u - (unsigned)(896 + wm * 64 + i * 16 + g4);
            #pragma unroll
            for (int r = 0; r < 4; ++r) {
                const unsigned idxv = ibase - (unsigned)r;
                #pragma unroll
                for (int j = 0; j < 4; ++j) {
                    unsigned c2 = (__float_as_uint(fmaxf(accB[i][j][r], 0.0f))
                                   & 0xFFFFFC00u) | idxv;
                    #pragma unroll
                    for (int p = 0; p < 5; ++p) {
                        unsigned mx = tl[j][p] > c2 ? tl[j][p] : c2;
                        unsigned mn = tl[j][p] > c2 ? c2 : tl[j][p];
                        tl[j][p] = mx; c2 = mn;
                    }
                }
            }
        }
    }

    __syncthreads();   // all LDS reads done; reuse smem as merge buffer
    unsigned (*mg)[41] = reinterpret_cast<unsigned (*)[41]>(smem);
    {
        const int c = lane & 15;
        const int src = wm * 4 + (lane >> 4);      // 0..7
        #pragma unroll
        for (int j = 0; j < 4; ++j) {
            const int l = wn * 64 + j * 16 + c;
            #pragma unroll
            for (int p = 0; p < 5; ++p)
                mg[l][src * 5 + p] = tl[j][p];
        }
    }
    __syncthreads();

    if (tid < 128) {
        unsigned best[8];
        #pragma unroll
        for (int p = 0; p < 8; ++p) best[p] = 0u;
        #pragma unroll
        for (int c = 0; c < 40; ++c) {
            unsigned key = mg[tid][c];
            #pragma unroll
            for (int p = 0; p < 8; ++p) {
                unsigned mx = best[p] > key ? best[p] : key;
                unsigned mn = best[p] > key ? key : best[p];
                best[p] = mx; key = mn;
            }
        }
        size_t gb = (((size_t)b * L_ + l0 + tid) * NCH + ch) * 8;
        #pragma unroll
        for (int p = 0; p < 8; ++p) pcand[gb + p] = best[p];
    }
}

// ---------------- Kernel 3: radix-select top-16, fp32 rescore, top-5,
//                  gather+mean, fused linear ----------------
__global__ __launch_bounds__(256) void tail_kernel(
    const float* __restrict__ enc, const float* __restrict__ mem,
    const float* __restrict__ invn,
    const unsigned int* __restrict__ pcand,
    const float* __restrict__ W, const float* __restrict__ bias,
    float* __restrict__ out)
{
    __shared__ float t_s[8][D_];
    __shared__ int cand_s[4][RESC];
    const int wv = threadIdx.x >> 6;
    const int lane = threadIdx.x & 63;
    const int row0 = blockIdx.x * 8 + wv * 2;

    #pragma unroll 1
    for (int r2 = 0; r2 < 2; ++r2) {
        const int row = row0 + r2;
        const int b = row >> 10;
        const int l = row & 1023;

        const size_t cb = (size_t)row * (NCH * 8);
        unsigned k0 = pcand[cb + lane], k1 = pcand[cb + 64 + lane];

        // radix-select: v = 16th largest of the 128 keys (exact, dup-safe)
        unsigned v = 0;
        #pragma unroll
        for (int bit = 31; bit >= 0; --bit) {
            unsigned t = v | (1u << bit);
            int c = __popcll(__ballot(k0 >= t)) + __popcll(__ballot(k1 >= t));
            v = (c >= RESC) ? t : v;
        }
        unsigned long long bA0 = __ballot(k0 > v), bA1 = __ballot(k1 > v);
        unsigned long long bE0 = __ballot(k0 == v), bE1 = __ballot(k1 == v);
        const int nA0 = __popcll(bA0);
        const int nA = nA0 + __popcll(bA1);
        const int need = RESC - nA;
        const unsigned long long lt = (1ull << lane) - 1ull;
        int s0 = -1, s1 = -1;
        if (k0 > v) s0 = __popcll(bA0 & lt);
        else if (k0 == v) { int r = __popcll(bE0 & lt); if (r < need) s0 = nA + r; }
        if (k1 > v) s1 = nA0 + __popcll(bA1 & lt);
        else if (k1 == v) { int r = __popcll(bE0) + __popcll(bE1 & lt); if (r < need) s1 = nA + r; }
        if (s0 >= 0)
            cand_s[wv][s0] = (lane >> 3) * CHUNK + (CHUNK - 1) - (int)(k0 & 1023u);
        if (s1 >= 0)
            cand_s[wv][s1] = (8 + (lane >> 3)) * CHUNK + (CHUNK - 1) - (int)(k1 & 1023u);
        asm volatile("s_waitcnt lgkmcnt(0)" ::: "memory");

        // fp32 rescore: lane -> candidate lane>>2, quarter lane&3
        const int ci = cand_s[wv][lane >> 2];
        const int q = lane & 3;
        const float4* er = reinterpret_cast<const float4*>(enc + ((size_t)b * L_ + l) * D_) + q * 16;
        const float4* mr = reinterpret_cast<const float4*>(mem + ((size_t)b * N_ + ci) * D_) + q * 16;
        float s = 0.0f;
        #pragma unroll
        for (int k = 0; k < 16; ++k) {
            float4 e = er[k], m = mr[k];
            s = fmaf(e.x, m.x, s); s = fmaf(e.y, m.y, s);
            s = fmaf(e.z, m.z, s); s = fmaf(e.w, m.w, s);
        }
        s += __shfl_xor(s, 1, 64);
        s += __shfl_xor(s, 2, 64);
        s *= invn[b * N_ + ci];

        float sw = s;
        int m0, m1, m2, m3, m4;
        #define PICK(MK) { \
            float mv = sw; int mi = ci; \
            if (sw == -FLT_MAX) mi = 0x7fffffff; \
            _Pragma("unroll") \
            for (int off = 32; off >= 4; off >>= 1) { \
                float ov = __shfl_xor(mv, off, 64); \
                int oi = __shfl_xor(mi, off, 64); \
                if (ov > mv || (ov == mv && oi < mi)) { mv = ov; mi = oi; } \
            } \
            MK = mi; \
            if (ci == mi) sw = -FLT_MAX; \
        }
        PICK(m0); PICK(m1); PICK(m2); PICK(m3); PICK(m4);
        #undef PICK

        const float4* eb = reinterpret_cast<const float4*>(enc + ((size_t)b * L_ + l) * D_);
        const float4* mb = reinterpret_cast<const float4*>(mem + (size_t)b * N_ * D_);
        float4 e = eb[lane];
        float4 a0 = mb[(size_t)m0 * 64 + lane];
        float4 a1 = mb[(size_t)m1 * 64 + lane];
        float4 a2 = mb[(size_t)m2 * 64 + lane];
        float4 a3 = mb[(size_t)m3 * 64 + lane];
        float4 a4 = mb[(size_t)m4 * 64 + lane];
        float4 o;
        o.x = e.x + 0.2f * (a0.x + a1.x + a2.x + a3.x + a4.x);
        o.y = e.y + 0.2f * (a0.y + a1.y + a2.y + a3.y + a4.y);
        o.z = e.z + 0.2f * (a0.z + a1.z + a2.z + a3.z + a4.z);
        o.w = e.w + 0.2f * (a0.w + a1.w + a2.w + a3.w + a4.w);
        *reinterpret_cast<float4*>(&t_s[wv * 2 + r2][lane * 4]) = o;
    }
    __syncthreads();

    // linear: thread = dout for all 8 rows
    const int dout = threadIdx.x;
    float accr[8];
    #pragma unroll
    for (int r = 0; r < 8; ++r) accr[r] = 0.0f;
    const float4* Wr = reinterpret_cast<const float4*>(W + (size_t)dout * D_);
    for (int d4 = 0; d4 < D_ / 4; ++d4) {
        float4 w = Wr[d4];
        #pragma unroll
        for (int r = 0; r < 8; ++r) {
            float4 t = *reinterpret_cast<const float4*>(&t_s[r][d4 * 4]);
            accr[r] = fmaf(w.x, t.x, accr[r]);
            accr[r] = fmaf(w.y, t.y, accr[r]);
            accr[r] = fmaf(w.z, t.z, accr[r]);
            accr[r] = fmaf(w.w, t.w, accr[r]);
        }
    }
    float bb = bias[dout];
    #pragma unroll
    for (int r = 0; r < 8; ++r)
        out[((size_t)blockIdx.x * 8 + r) * D_ + dout] = accr[r] + bb;
}

extern "C" void kernel_launch(void* const* d_in, const int* in_sizes, int n_in,
                              void* d_out, int out_size, void* d_ws, size_t ws_size,
                              hipStream_t stream)
{
    (void)in_sizes; (void)n_in; (void)out_size;
    const float* enc  = (const float*)d_in[0];
    const float* mem  = (const float*)d_in[1];
    const float* W    = (const float*)d_in[2];
    const float* bias = (const float*)d_in[3];
    float* out = (float*)d_out;

    const size_t sz_memn = (size_t)B_ * N_ * D_ * 2;        // 32 MiB
    const size_t sz_enc  = (size_t)B_ * L_ * D_ * 2;        // 2 MiB
    const size_t sz_invn = (size_t)B_ * N_ * 4;             // 256 KiB
    const size_t sz_pc   = (size_t)B_ * L_ * NCH * 8 * 4;   // 2 MiB
    const size_t need = sz_memn + sz_enc + sz_invn + sz_pc;
    if (ws_size < need) return;

    char* p = (char*)d_ws;
    unsigned short* memn_bf = (unsigned short*)p;  p += sz_memn;
    unsigned short* enc_bf  = (unsigned short*)p;  p += sz_enc;
    float* invn = (float*)p;  p += sz_invn;
    unsigned int* pcand = (unsigned int*)p;

    {
        int rows = B_ * N_ + B_ * L_;
        prep_kernel<<<(rows + 3) / 4, 256, 0, stream>>>(enc, mem, invn, memn_bf, enc_bf);
    }
    {
        dim3 grid(NCH, L_ / 128, B_);
        screen_kernel<<<grid, 256, 0, stream>>>(enc_bf, memn_bf, pcand);
    }
    {
        tail_kernel<<<(B_ * L_) / 8, 256, 0, stream>>>(enc, mem, invn, pcand, W, bias, out);
    }
}